// Round 10
// baseline (277.522 us; speedup 1.0000x reference)
//
#include <hip/hip_runtime.h>
#include <math.h>

#define NPX 16384   // 128*128

static constexpr float  PI_F   = 3.14159265358979323846f;
static constexpr double PI_D   = 3.14159265358979323846;
static constexpr double STEP_D = PI_D / 180.0;              // np.linspace step (f64)
static constexpr double BW_D   = 15.0 * (PI_D / 180.0);     // math.radians(15)

typedef float f4 __attribute__((ext_vector_type(4)));
typedef float f2 __attribute__((ext_vector_type(2)));

__device__ __forceinline__ int swz(int r, int c) {
    // XOR-Gray swizzle: row r, col c -> LDS element index. Minimum-phase for
    // both row- and column-wise wave access (float2 elements).
    return (r << 7) | (c ^ (r ^ (r >> 1)));
}
__device__ __forceinline__ int brev7(int x) { return (int)(__brev((unsigned)x) >> 25); }
__device__ __forceinline__ float2 cadd(float2 a, float2 b){ return make_float2(a.x+b.x, a.y+b.y); }
__device__ __forceinline__ float2 csub(float2 a, float2 b){ return make_float2(a.x-b.x, a.y-b.y); }
__device__ __forceinline__ float2 cmul(float2 a, float re, float im){
    return make_float2(a.x*re - a.y*im, a.x*im + a.y*re);
}
__device__ __forceinline__ double edge_d(int i) {           // np.linspace(0, pi, 181) f64
    return (i >= 180) ? PI_D : (double)i * STEP_D;          // endpoint forced to stop
}

// ---------------- K0: per-pixel tables in FFT-STORAGE order + zero energy -----------
__global__ void k0_tables(double* __restrict__ theta_s, int* __restrict__ bin_s,
                          double* __restrict__ energy) {
    int p = blockIdx.x * blockDim.x + threadIdx.x;
    if (p < NPX) {
        int r = p >> 7, c = p & 127;
        int pix = ((brev7(r) ^ 64) << 7) | (brev7(c) ^ 64);
        int h = pix >> 7, w = pix & 127;
        double dy = (double)(h - 64), dx = (double)(w - 64);
        double theta = atan2(dy, dx) + PI_D;                 // [0, 2pi], f64 like np
        theta_s[p] = theta;
        double v = fmod(theta, PI_D);                        // np % for positive args
        int cnt = 0;                                         // searchsorted 'left' - 1
        for (int i = 0; i <= 180; ++i) cnt += (edge_d(i) < v) ? 1 : 0;
        int bin = cnt - 1;
        if (bin < 0) bin = 0;
        if (bin > 179) bin = 179;
        int r2 = (h - 64)*(h - 64) + (w - 64)*(w - 64);
        bool high = (r2 >= 369);                             // r > 19.2 (no integer tie)
        bin_s[p] = high ? bin : -1;
    }
    if (blockIdx.x == 0) {
        for (int i = threadIdx.x; i < 16 * 180; i += blockDim.x) energy[i] = 0.0;
    }
}

// ---------------- K1: partial x_proj, 2-way channel split for occupancy --------------
__global__ __launch_bounds__(256, 1) void k1_proj(const float* __restrict__ x,
        const float* __restrict__ w_in, float* __restrict__ xpp) {
    int b = blockIdx.y, z = blockIdx.z;
    int t4 = blockIdx.x * blockDim.x + threadIdx.x;   // float4 index, 0..4095
    const f4* xb = (const f4*)(x + ((size_t)b * 256 + (size_t)z * 128) * NPX);
    f4 acc[16];
    #pragma unroll
    for (int m = 0; m < 16; ++m) acc[m] = (f4)0.0f;
    #pragma unroll 16
    for (int c = 0; c < 128; ++c) {
        f4 xv = xb[(size_t)c * (NPX/4) + t4];
        #pragma unroll
        for (int m = 0; m < 16; ++m) {
            float wv = w_in[m * 256 + z * 128 + c];
            acc[m] += wv * xv;
        }
    }
    f4* xp = (f4*)xpp + ((size_t)z * 256 + b * 16) * (NPX/4);
    #pragma unroll
    for (int m = 0; m < 16; ++m) xp[(size_t)m * (NPX/4) + t4] = acc[m];
}

// ---------------- K2: sum partials, forward 2D FFT (radix-4 DIF) + f64 histogram -----
__global__ __launch_bounds__(1024) void k_fft_fwd(const float* __restrict__ xpp,
        float2* __restrict__ fs, const int* __restrict__ bin_s,
        double* __restrict__ energy) {
    extern __shared__ float2 lds[];        // 16384 float2 = 128 KB, swizzled
    __shared__ float twr[64], twi[64];
    __shared__ double histp[8][180];       // private partials, 8x less contention
    const int tid = threadIdx.x;
    const int img = blockIdx.x;            // = b*16 + m
    if (tid < 64) {
        float ang = (float)tid * (PI_F / 64.0f);   // 2*pi*k/128
        twr[tid] = cosf(ang);
        twi[tid] = sinf(ang);
    }
    if (tid < 180) {
        #pragma unroll
        for (int g = 0; g < 8; ++g) histp[g][tid] = 0.0;
    }
    const f4* s0 = (const f4*)xpp + (size_t)img * (NPX/4);
    const f4* s1 = (const f4*)xpp + (size_t)(256 + img) * (NPX/4);
    #pragma unroll
    for (int it = 0; it < 4; ++it) {
        int p4 = tid + it * 1024;
        f4 v = s0[p4] + s1[p4];            // combine channel partials
        int pb = p4 * 4;
        #pragma unroll
        for (int j = 0; j < 4; ++j) {
            int p = pb + j;
            lds[swz(p >> 7, p & 127)] = make_float2(v[j], 0.0f);
        }
    }
    __syncthreads();
    #pragma unroll
    for (int dim = 0; dim < 2; ++dim) {
        // radix-4 passes: stage pairs (0,1), (2,3), (4,5)
        #pragma unroll
        for (int s = 0; s <= 4; s += 2) {
            const int q = 32 >> s;
            #pragma unroll
            for (int it = 0; it < 4; ++it) {
                int fb = tid + it * 1024;
                int o = fb & 127;
                int bfi = fb >> 7;               // 0..31
                int p = bfi & (q - 1);
                int g = bfi >> (5 - s);
                int P = g * (128 >> s) + p;
                int k1 = p << s;                 // < 32
                float tc = twr[k1],   ts = twi[k1];
                float uc = twr[2*k1], us = twi[2*k1];
                int e0, e1, e2, e3;
                if (dim == 0) { e0=swz(o,P); e1=swz(o,P+q); e2=swz(o,P+2*q); e3=swz(o,P+3*q); }
                else          { e0=swz(P,o); e1=swz(P+q,o); e2=swz(P+2*q,o); e3=swz(P+3*q,o); }
                float2 a = lds[e0], b = lds[e1], c = lds[e2], d = lds[e3];
                float2 u0 = cadd(a, c);
                float2 u1 = cmul(csub(a, c), tc, -ts);       // * W^k1
                float2 v0 = cadd(b, d);
                float2 v1 = cmul(csub(b, d), -ts, -tc);      // * W^(k1+32)
                lds[e0] = cadd(u0, v0);
                lds[e1] = cmul(csub(u0, v0), uc, -us);       // * W^(2k1)
                lds[e2] = cadd(u1, v1);
                lds[e3] = cmul(csub(u1, v1), uc, -us);
            }
            __syncthreads();
        }
        // radix-2 stage 6 (twiddle = 1)
        #pragma unroll
        for (int it = 0; it < 8; ++it) {
            int fb = tid + it * 1024;
            int o = fb & 127;
            int g = fb >> 7;                     // 0..63
            int e0, e1;
            if (dim == 0) { e0 = swz(o, 2*g); e1 = swz(o, 2*g+1); }
            else          { e0 = swz(2*g, o); e1 = swz(2*g+1, o); }
            float2 a = lds[e0], b = lds[e1];
            lds[e0] = cadd(a, b);
            lds[e1] = csub(a, b);
        }
        __syncthreads();
    }
    // store fs (storage order) + f64 angular histogram; bin_s is coalesced.
    float2* dst = fs + (size_t)img * NPX;
    const int bofs = (img >> 4) * 180;
    const int grp = tid >> 7;                    // 128 threads per private group
    #pragma unroll
    for (int it = 0; it < 16; ++it) {
        int p = tid + it * 1024;
        int r = p >> 7, c = p & 127;
        float2 v = lds[swz(r, c)];
        dst[p] = v;
        int bh = bin_s[p];
        if (bh >= 0) {
            double m = sqrt((double)v.x * (double)v.x + (double)v.y * (double)v.y);
            atomicAdd(&histp[grp][bh], m);
        }
    }
    __syncthreads();
    if (tid < 180) {
        double s = 0.0;
        #pragma unroll
        for (int g = 0; g < 8; ++g) s += histp[g][tid];
        atomicAdd(&energy[bofs + tid], s);
    }
}

// ---------------- K3: f64 smoothing + peaks + top2 + gain map (storage order) ---------
__global__ void k3_peaks(const double* __restrict__ energy, const double* __restrict__ theta_s,
                         const int* __restrict__ bin_s, float* __restrict__ gain_s) {
    __shared__ double e[180], es[180];
    __shared__ double pa[2];
    int b = blockIdx.x, tid = threadIdx.x;
    if (tid < 180) e[tid] = energy[b * 180 + tid];
    __syncthreads();
    if (tid < 180) {
        double l = (tid > 0)   ? e[tid-1] : 0.0;    // zero padding
        double r = (tid < 179) ? e[tid+1] : 0.0;
        es[tid] = 0.25*l + 0.5*e[tid] + 0.25*r;     // products exact (pow2)
    }
    __syncthreads();
    if (tid == 0) {
        double sum = 0.0;
        for (int i = 0; i < 180; ++i) sum += es[i];
        double mean = sum / 180.0;
        double v0 = -INFINITY, v1 = -INFINITY;
        int   i0 = -1, i1 = -1;
        for (int i = 0; i < 180; ++i) {
            double prev = es[(i + 179) % 180];       // jnp.roll is cyclic
            double nxt  = es[(i + 1) % 180];
            bool pk = (es[i] > mean) && (es[i] > prev) && (es[i] > nxt);
            if (pk) {
                double v = es[i];
                if (v > v0)      { v1 = v0; i1 = i0; v0 = v; i0 = i; }
                else if (v > v1) { v1 = v;  i1 = i; }
            }
        }
        int idx0, idx1;
        if (i0 < 0) {
            double mv = es[0]; int mi = 0;
            for (int i = 1; i < 180; ++i) if (es[i] > mv) { mv = es[i]; mi = i; }
            idx0 = idx1 = mi;
        } else if (i1 < 0) { idx0 = idx1 = i0; }
        else               { idx0 = i0; idx1 = i1; }
        pa[0] = (edge_d(idx0) + edge_d(idx0 + 1)) * 0.5;
        pa[1] = (edge_d(idx1) + edge_d(idx1 + 1)) * 0.5;
    }
    __syncthreads();
    double pa0 = pa[0], pa1 = pa[1];
    for (int p = tid; p < NPX; p += blockDim.x) {     // fully coalesced
        double th = theta_s[p];
        bool high = bin_s[p] >= 0;
        double d0 = fabs(th - pa0); d0 = fmin(d0, PI_D - d0);  // incl. negative quirk
        double d1 = fabs(th - pa1); d1 = fmin(d1, PI_D - d1);
        bool enh = ((d0 <= BW_D) || (d1 <= BW_D)) && high;
        float g = enh ? 1.2f : (high ? 0.8f : 1.0f);
        gain_s[(size_t)b * NPX + p] = g * (1.0f / 16384.0f);   // fold ortho norms
    }
}

// ---------------- K4: gain * fs, inverse 2D FFT (radix-4 DIT from bitrev) -------------
__global__ __launch_bounds__(1024) void k_fft_inv(const float2* __restrict__ fs,
        const float* __restrict__ gain_s, float* __restrict__ xe) {
    extern __shared__ float2 lds[];
    __shared__ float twr[64], twi[64];
    const int tid = threadIdx.x;
    const int img = blockIdx.x;
    if (tid < 64) {
        float ang = (float)tid * (PI_F / 64.0f);
        twr[tid] = cosf(ang);
        twi[tid] = sinf(ang);
    }
    const f4* srcv = (const f4*)(fs + (size_t)img * NPX);      // 2 px per f4
    const f2* gbv  = (const f2*)(gain_s + (size_t)(img >> 4) * NPX);
    #pragma unroll
    for (int it = 0; it < 8; ++it) {
        int q = tid + it * 1024;               // 0..8191
        f4 v = srcv[q];
        f2 g = gbv[q];
        int p = q * 2;
        lds[swz(p >> 7, p & 127)]             = make_float2(v.x * g.x, v.y * g.x);
        lds[swz((p+1) >> 7, (p+1) & 127)]     = make_float2(v.z * g.y, v.w * g.y);
    }
    __syncthreads();
    #pragma unroll
    for (int dim = 0; dim < 2; ++dim) {
        // inverse radix-2 stage 6 first (same butterfly, tw = 1)
        #pragma unroll
        for (int it = 0; it < 8; ++it) {
            int fb = tid + it * 1024;
            int o = fb & 127;
            int g = fb >> 7;
            int e0, e1;
            if (dim == 0) { e0 = swz(o, 2*g); e1 = swz(o, 2*g+1); }
            else          { e0 = swz(2*g, o); e1 = swz(2*g+1, o); }
            float2 a = lds[e0], b = lds[e1];
            lds[e0] = cadd(a, b);
            lds[e1] = csub(a, b);
        }
        __syncthreads();
        // inverse radix-4 passes: (5,4), (3,2), (1,0)
        #pragma unroll
        for (int s = 4; s >= 0; s -= 2) {
            const int q = 32 >> s;
            #pragma unroll
            for (int it = 0; it < 4; ++it) {
                int fb = tid + it * 1024;
                int o = fb & 127;
                int bfi = fb >> 7;
                int p = bfi & (q - 1);
                int g = bfi >> (5 - s);
                int P = g * (128 >> s) + p;
                int k1 = p << s;
                float tc = twr[k1],   ts = twi[k1];
                float uc = twr[2*k1], us = twi[2*k1];
                int e0, e1, e2, e3;
                if (dim == 0) { e0=swz(o,P); e1=swz(o,P+q); e2=swz(o,P+2*q); e3=swz(o,P+3*q); }
                else          { e0=swz(P,o); e1=swz(P+q,o); e2=swz(P+2*q,o); e3=swz(P+3*q,o); }
                float2 o0 = lds[e0], o1 = lds[e1], o2 = lds[e2], o3 = lds[e3];
                float2 t1 = cmul(o1, uc, us);       // * conj(W^2k1)
                float2 u0 = cadd(o0, t1);
                float2 v0 = csub(o0, t1);
                float2 t3 = cmul(o3, uc, us);
                float2 u1 = cadd(o2, t3);
                float2 v1 = csub(o2, t3);
                float2 ta = cmul(u1, tc, ts);       // * conj(W^k1)
                float2 tb = cmul(v1, -ts, tc);      // * conj(W^(k1+32))
                lds[e0] = cadd(u0, ta);
                lds[e2] = csub(u0, ta);
                lds[e1] = cadd(v0, tb);
                lds[e3] = csub(v0, tb);
            }
            __syncthreads();
        }
    }
    float* dstx = xe + (size_t)img * NPX;
    #pragma unroll
    for (int it = 0; it < 16; ++it) {
        int p = tid + it * 1024;
        dstx[p] = lds[swz(p >> 7, p & 127)].x;
    }
}

// ---------------- K5: out = x + w_out @ xe (plain stores this round) -----------------
__global__ __launch_bounds__(256, 1) void k5_out(const float* __restrict__ x,
        const float* __restrict__ w_out, const float* __restrict__ xe,
        float* __restrict__ out) {
    int b = blockIdx.z, ct = blockIdx.y, pt = blockIdx.x, t = threadIdx.x;
    int p4 = pt * 256 + t;                   // float4 index 0..4095
    const f4* xeb = (const f4*)(xe + (size_t)b * 16 * NPX);
    f4 xv[16];
    #pragma unroll
    for (int m = 0; m < 16; ++m) xv[m] = xeb[(size_t)m * (NPX/4) + p4];
    #pragma unroll 8
    for (int cc = 0; cc < 16; ++cc) {
        int c = ct * 16 + cc;
        size_t base = ((size_t)b * 256 + c) * NPX;
        f4 a = ((const f4*)(x + base))[p4];
        #pragma unroll
        for (int m = 0; m < 16; ++m) {
            float wv = w_out[c * 16 + m];
            a += wv * xv[m];
        }
        ((f4*)(out + base))[p4] = a;         // plain store (was NT)
    }
}

extern "C" void kernel_launch(void* const* d_in, const int* in_sizes, int n_in,
                              void* d_out, int out_size, void* d_ws, size_t ws_size,
                              hipStream_t stream) {
    const float* x     = (const float*)d_in[0];
    const float* w_in  = (const float*)d_in[1];
    const float* w_out = (const float*)d_in[2];
    float* out = (float*)d_out;
    char* ws = (char*)d_ws;

    double* theta_s = (double*)(ws);                    // 128 KB (storage order)
    int*    bin_s   = (int*)   (ws + 0x20000);          //  64 KB (storage order)
    double* energy  = (double*)(ws + 0x30000);          //  16*180*8 B
    float*  gain_s  = (float*) (ws + 0x40000);          //   1 MB
    float*  xe      = (float*) (ws + 0x140000);         //  16 MB
    // Dead-interval reuse of d_out (256 MiB, K5 rewrites all of it last):
    //   xpp (34 MB partial x_proj) at +128 MiB, dead after K2 reads it.
    //   fs  (32 MB spectra)        at +224 MiB, dead after K4 reads it.
    float*  xpp = (float*)((char*)d_out + ((size_t)128 << 20));
    float2* fs  = (float2*)((char*)d_out + ((size_t)224 << 20));

    (void)hipFuncSetAttribute((const void*)k_fft_fwd,
            hipFuncAttributeMaxDynamicSharedMemorySize, 131072);
    (void)hipFuncSetAttribute((const void*)k_fft_inv,
            hipFuncAttributeMaxDynamicSharedMemorySize, 131072);

    k0_tables<<<dim3(64), dim3(256), 0, stream>>>(theta_s, bin_s, energy);
    k1_proj  <<<dim3(16, 16, 2), dim3(256), 0, stream>>>(x, w_in, xpp);
    k_fft_fwd<<<dim3(256), dim3(1024), 131072, stream>>>(xpp, fs, bin_s, energy);
    k3_peaks <<<dim3(16), dim3(256), 0, stream>>>(energy, theta_s, bin_s, gain_s);
    k_fft_inv<<<dim3(256), dim3(1024), 131072, stream>>>(fs, gain_s, xe);
    k5_out   <<<dim3(16, 16, 16), dim3(256), 0, stream>>>(x, w_out, xe, out);
}

// Round 11
// 246.832 us; speedup vs baseline: 1.1243x; 1.1243x over previous
//
#include <hip/hip_runtime.h>
#include <math.h>

#define NPX 16384   // 128*128

static constexpr float  PI_F   = 3.14159265358979323846f;
static constexpr double PI_D   = 3.14159265358979323846;
static constexpr double STEP_D = PI_D / 180.0;              // np.linspace step (f64)
static constexpr double BW_D   = 15.0 * (PI_D / 180.0);     // math.radians(15)

typedef float f4 __attribute__((ext_vector_type(4)));
typedef float f2 __attribute__((ext_vector_type(2)));

__device__ __forceinline__ int swz(int r, int c) {
    // XOR-Gray swizzle: row r, col c -> LDS element index. Minimum-phase for
    // both row- and column-wise wave access (float2 elements).
    return (r << 7) | (c ^ (r ^ (r >> 1)));
}
__device__ __forceinline__ int brev7(int x) { return (int)(__brev((unsigned)x) >> 25); }
__device__ __forceinline__ float2 cadd(float2 a, float2 b){ return make_float2(a.x+b.x, a.y+b.y); }
__device__ __forceinline__ float2 csub(float2 a, float2 b){ return make_float2(a.x-b.x, a.y-b.y); }
__device__ __forceinline__ float2 cmul(float2 a, float re, float im){
    return make_float2(a.x*re - a.y*im, a.x*im + a.y*re);
}
__device__ __forceinline__ double edge_d(int i) {           // np.linspace(0, pi, 181) f64
    return (i >= 180) ? PI_D : (double)i * STEP_D;          // endpoint forced to stop
}

// ---------------- K0: per-pixel tables in FFT-STORAGE order + zero energy -----------
__global__ void k0_tables(double* __restrict__ theta_s, int* __restrict__ bin_s,
                          double* __restrict__ energy) {
    int p = blockIdx.x * blockDim.x + threadIdx.x;
    if (p < NPX) {
        int r = p >> 7, c = p & 127;
        int pix = ((brev7(r) ^ 64) << 7) | (brev7(c) ^ 64);
        int h = pix >> 7, w = pix & 127;
        double dy = (double)(h - 64), dx = (double)(w - 64);
        double theta = atan2(dy, dx) + PI_D;                 // [0, 2pi], f64 like np
        theta_s[p] = theta;
        double v = fmod(theta, PI_D);                        // np % for positive args
        int cnt = 0;                                         // searchsorted 'left' - 1
        for (int i = 0; i <= 180; ++i) cnt += (edge_d(i) < v) ? 1 : 0;
        int bin = cnt - 1;
        if (bin < 0) bin = 0;
        if (bin > 179) bin = 179;
        int r2 = (h - 64)*(h - 64) + (w - 64)*(w - 64);
        bool high = (r2 >= 369);                             // r > 19.2 (no integer tie)
        bin_s[p] = high ? bin : -1;
    }
    if (blockIdx.x == 0) {
        for (int i = threadIdx.x; i < 16 * 180; i += blockDim.x) energy[i] = 0.0;
    }
}

// ---------------- K1: partial x_proj, 2-way channel split; NT x loads ----------------
__global__ __launch_bounds__(256, 1) void k1_proj(const float* __restrict__ x,
        const float* __restrict__ w_in, float* __restrict__ xpp) {
    int b = blockIdx.y, z = blockIdx.z;
    int t4 = blockIdx.x * blockDim.x + threadIdx.x;   // float4 index, 0..4095
    const f4* xb = (const f4*)(x + ((size_t)b * 256 + (size_t)z * 128) * NPX);
    f4 acc[16];
    #pragma unroll
    for (int m = 0; m < 16; ++m) acc[m] = (f4)0.0f;
    #pragma unroll 16
    for (int c = 0; c < 128; ++c) {
        f4 xv = __builtin_nontemporal_load(&xb[(size_t)c * (NPX/4) + t4]);
        #pragma unroll
        for (int m = 0; m < 16; ++m) {
            float wv = w_in[m * 256 + z * 128 + c];
            acc[m] += wv * xv;
        }
    }
    f4* xp = (f4*)xpp + ((size_t)z * 256 + b * 16) * (NPX/4);
    #pragma unroll
    for (int m = 0; m < 16; ++m) xp[(size_t)m * (NPX/4) + t4] = acc[m];
}

// ---------------- K2: sum partials, forward 2D FFT (radix-4 DIF) + f64 histogram -----
__global__ __launch_bounds__(1024) void k_fft_fwd(const float* __restrict__ xpp,
        float2* __restrict__ fs, const int* __restrict__ bin_s,
        double* __restrict__ energy) {
    extern __shared__ float2 lds[];        // 16384 float2 = 128 KB, swizzled
    __shared__ float twr[64], twi[64];
    __shared__ double histp[8][180];       // private partials, 8x less contention
    const int tid = threadIdx.x;
    const int img = blockIdx.x;            // = b*16 + m
    if (tid < 64) {
        float ang = (float)tid * (PI_F / 64.0f);   // 2*pi*k/128
        twr[tid] = cosf(ang);
        twi[tid] = sinf(ang);
    }
    if (tid < 180) {
        #pragma unroll
        for (int g = 0; g < 8; ++g) histp[g][tid] = 0.0;
    }
    const f4* s0 = (const f4*)xpp + (size_t)img * (NPX/4);
    const f4* s1 = (const f4*)xpp + (size_t)(256 + img) * (NPX/4);
    #pragma unroll
    for (int it = 0; it < 4; ++it) {
        int p4 = tid + it * 1024;
        f4 v = s0[p4] + s1[p4];            // combine channel partials
        int pb = p4 * 4;
        #pragma unroll
        for (int j = 0; j < 4; ++j) {
            int p = pb + j;
            lds[swz(p >> 7, p & 127)] = make_float2(v[j], 0.0f);
        }
    }
    __syncthreads();
    #pragma unroll
    for (int dim = 0; dim < 2; ++dim) {
        // radix-4 passes: stage pairs (0,1), (2,3), (4,5)
        #pragma unroll
        for (int s = 0; s <= 4; s += 2) {
            const int q = 32 >> s;
            #pragma unroll
            for (int it = 0; it < 4; ++it) {
                int fb = tid + it * 1024;
                int o = fb & 127;
                int bfi = fb >> 7;               // 0..31
                int p = bfi & (q - 1);
                int g = bfi >> (5 - s);
                int P = g * (128 >> s) + p;
                int k1 = p << s;                 // < 32
                float tc = twr[k1],   ts = twi[k1];
                float uc = twr[2*k1], us = twi[2*k1];
                int e0, e1, e2, e3;
                if (dim == 0) { e0=swz(o,P); e1=swz(o,P+q); e2=swz(o,P+2*q); e3=swz(o,P+3*q); }
                else          { e0=swz(P,o); e1=swz(P+q,o); e2=swz(P+2*q,o); e3=swz(P+3*q,o); }
                float2 a = lds[e0], b = lds[e1], c = lds[e2], d = lds[e3];
                float2 u0 = cadd(a, c);
                float2 u1 = cmul(csub(a, c), tc, -ts);       // * W^k1
                float2 v0 = cadd(b, d);
                float2 v1 = cmul(csub(b, d), -ts, -tc);      // * W^(k1+32)
                lds[e0] = cadd(u0, v0);
                lds[e1] = cmul(csub(u0, v0), uc, -us);       // * W^(2k1)
                lds[e2] = cadd(u1, v1);
                lds[e3] = cmul(csub(u1, v1), uc, -us);
            }
            __syncthreads();
        }
        // radix-2 stage 6 (twiddle = 1)
        #pragma unroll
        for (int it = 0; it < 8; ++it) {
            int fb = tid + it * 1024;
            int o = fb & 127;
            int g = fb >> 7;                     // 0..63
            int e0, e1;
            if (dim == 0) { e0 = swz(o, 2*g); e1 = swz(o, 2*g+1); }
            else          { e0 = swz(2*g, o); e1 = swz(2*g+1, o); }
            float2 a = lds[e0], b = lds[e1];
            lds[e0] = cadd(a, b);
            lds[e1] = csub(a, b);
        }
        __syncthreads();
    }
    // store fs (storage order) + f64 angular histogram; bin_s is coalesced.
    float2* dst = fs + (size_t)img * NPX;
    const int bofs = (img >> 4) * 180;
    const int grp = tid >> 7;                    // 128 threads per private group
    #pragma unroll
    for (int it = 0; it < 16; ++it) {
        int p = tid + it * 1024;
        int r = p >> 7, c = p & 127;
        float2 v = lds[swz(r, c)];
        dst[p] = v;
        int bh = bin_s[p];
        if (bh >= 0) {
            double m = sqrt((double)v.x * (double)v.x + (double)v.y * (double)v.y);
            atomicAdd(&histp[grp][bh], m);
        }
    }
    __syncthreads();
    if (tid < 180) {
        double s = 0.0;
        #pragma unroll
        for (int g = 0; g < 8; ++g) s += histp[g][tid];
        atomicAdd(&energy[bofs + tid], s);
    }
}

// ---------------- K3: f64 smoothing + peaks + top2 + gain map (storage order) ---------
__global__ void k3_peaks(const double* __restrict__ energy, const double* __restrict__ theta_s,
                         const int* __restrict__ bin_s, float* __restrict__ gain_s) {
    __shared__ double e[180], es[180];
    __shared__ double pa[2];
    int b = blockIdx.x, tid = threadIdx.x;
    if (tid < 180) e[tid] = energy[b * 180 + tid];
    __syncthreads();
    if (tid < 180) {
        double l = (tid > 0)   ? e[tid-1] : 0.0;    // zero padding
        double r = (tid < 179) ? e[tid+1] : 0.0;
        es[tid] = 0.25*l + 0.5*e[tid] + 0.25*r;     // products exact (pow2)
    }
    __syncthreads();
    if (tid == 0) {
        double sum = 0.0;
        for (int i = 0; i < 180; ++i) sum += es[i];
        double mean = sum / 180.0;
        double v0 = -INFINITY, v1 = -INFINITY;
        int   i0 = -1, i1 = -1;
        for (int i = 0; i < 180; ++i) {
            double prev = es[(i + 179) % 180];       // jnp.roll is cyclic
            double nxt  = es[(i + 1) % 180];
            bool pk = (es[i] > mean) && (es[i] > prev) && (es[i] > nxt);
            if (pk) {
                double v = es[i];
                if (v > v0)      { v1 = v0; i1 = i0; v0 = v; i0 = i; }
                else if (v > v1) { v1 = v;  i1 = i; }
            }
        }
        int idx0, idx1;
        if (i0 < 0) {
            double mv = es[0]; int mi = 0;
            for (int i = 1; i < 180; ++i) if (es[i] > mv) { mv = es[i]; mi = i; }
            idx0 = idx1 = mi;
        } else if (i1 < 0) { idx0 = idx1 = i0; }
        else               { idx0 = i0; idx1 = i1; }
        pa[0] = (edge_d(idx0) + edge_d(idx0 + 1)) * 0.5;
        pa[1] = (edge_d(idx1) + edge_d(idx1 + 1)) * 0.5;
    }
    __syncthreads();
    double pa0 = pa[0], pa1 = pa[1];
    for (int p = tid; p < NPX; p += blockDim.x) {     // fully coalesced
        double th = theta_s[p];
        bool high = bin_s[p] >= 0;
        double d0 = fabs(th - pa0); d0 = fmin(d0, PI_D - d0);  // incl. negative quirk
        double d1 = fabs(th - pa1); d1 = fmin(d1, PI_D - d1);
        bool enh = ((d0 <= BW_D) || (d1 <= BW_D)) && high;
        float g = enh ? 1.2f : (high ? 0.8f : 1.0f);
        gain_s[(size_t)b * NPX + p] = g * (1.0f / 16384.0f);   // fold ortho norms
    }
}

// ---------------- K4: gain * fs, inverse 2D FFT (radix-4 DIT from bitrev) -------------
__global__ __launch_bounds__(1024) void k_fft_inv(const float2* __restrict__ fs,
        const float* __restrict__ gain_s, float* __restrict__ xe) {
    extern __shared__ float2 lds[];
    __shared__ float twr[64], twi[64];
    const int tid = threadIdx.x;
    const int img = blockIdx.x;
    if (tid < 64) {
        float ang = (float)tid * (PI_F / 64.0f);
        twr[tid] = cosf(ang);
        twi[tid] = sinf(ang);
    }
    const f4* srcv = (const f4*)(fs + (size_t)img * NPX);      // 2 px per f4
    const f2* gbv  = (const f2*)(gain_s + (size_t)(img >> 4) * NPX);
    #pragma unroll
    for (int it = 0; it < 8; ++it) {
        int q = tid + it * 1024;               // 0..8191
        f4 v = srcv[q];
        f2 g = gbv[q];
        int p = q * 2;
        lds[swz(p >> 7, p & 127)]             = make_float2(v.x * g.x, v.y * g.x);
        lds[swz((p+1) >> 7, (p+1) & 127)]     = make_float2(v.z * g.y, v.w * g.y);
    }
    __syncthreads();
    #pragma unroll
    for (int dim = 0; dim < 2; ++dim) {
        // inverse radix-2 stage 6 first (same butterfly, tw = 1)
        #pragma unroll
        for (int it = 0; it < 8; ++it) {
            int fb = tid + it * 1024;
            int o = fb & 127;
            int g = fb >> 7;
            int e0, e1;
            if (dim == 0) { e0 = swz(o, 2*g); e1 = swz(o, 2*g+1); }
            else          { e0 = swz(2*g, o); e1 = swz(2*g+1, o); }
            float2 a = lds[e0], b = lds[e1];
            lds[e0] = cadd(a, b);
            lds[e1] = csub(a, b);
        }
        __syncthreads();
        // inverse radix-4 passes: (5,4), (3,2), (1,0)
        #pragma unroll
        for (int s = 4; s >= 0; s -= 2) {
            const int q = 32 >> s;
            #pragma unroll
            for (int it = 0; it < 4; ++it) {
                int fb = tid + it * 1024;
                int o = fb & 127;
                int bfi = fb >> 7;
                int p = bfi & (q - 1);
                int g = bfi >> (5 - s);
                int P = g * (128 >> s) + p;
                int k1 = p << s;
                float tc = twr[k1],   ts = twi[k1];
                float uc = twr[2*k1], us = twi[2*k1];
                int e0, e1, e2, e3;
                if (dim == 0) { e0=swz(o,P); e1=swz(o,P+q); e2=swz(o,P+2*q); e3=swz(o,P+3*q); }
                else          { e0=swz(P,o); e1=swz(P+q,o); e2=swz(P+2*q,o); e3=swz(P+3*q,o); }
                float2 o0 = lds[e0], o1 = lds[e1], o2 = lds[e2], o3 = lds[e3];
                float2 t1 = cmul(o1, uc, us);       // * conj(W^2k1)
                float2 u0 = cadd(o0, t1);
                float2 v0 = csub(o0, t1);
                float2 t3 = cmul(o3, uc, us);
                float2 u1 = cadd(o2, t3);
                float2 v1 = csub(o2, t3);
                float2 ta = cmul(u1, tc, ts);       // * conj(W^k1)
                float2 tb = cmul(v1, -ts, tc);      // * conj(W^(k1+32))
                lds[e0] = cadd(u0, ta);
                lds[e2] = csub(u0, ta);
                lds[e1] = cadd(v0, tb);
                lds[e3] = csub(v0, tb);
            }
            __syncthreads();
        }
    }
    float* dstx = xe + (size_t)img * NPX;
    #pragma unroll
    for (int it = 0; it < 16; ++it) {
        int p = tid + it * 1024;
        dstx[p] = lds[swz(p >> 7, p & 127)].x;
    }
}

// ---------------- K5: out = x + w_out @ xe (NT x loads + NT stores) ------------------
__global__ __launch_bounds__(256, 1) void k5_out(const float* __restrict__ x,
        const float* __restrict__ w_out, const float* __restrict__ xe,
        float* __restrict__ out) {
    int b = blockIdx.z, ct = blockIdx.y, pt = blockIdx.x, t = threadIdx.x;
    int p4 = pt * 256 + t;                   // float4 index 0..4095
    const f4* xeb = (const f4*)(xe + (size_t)b * 16 * NPX);
    f4 xv[16];
    #pragma unroll
    for (int m = 0; m < 16; ++m) xv[m] = xeb[(size_t)m * (NPX/4) + p4];
    #pragma unroll 8
    for (int cc = 0; cc < 16; ++cc) {
        int c = ct * 16 + cc;
        size_t base = ((size_t)b * 256 + c) * NPX;
        f4 a = __builtin_nontemporal_load((const f4*)(x + base) + p4);
        #pragma unroll
        for (int m = 0; m < 16; ++m) {
            float wv = w_out[c * 16 + m];
            a += wv * xv[m];
        }
        __builtin_nontemporal_store(a, (f4*)(out + base) + p4);
    }
}

extern "C" void kernel_launch(void* const* d_in, const int* in_sizes, int n_in,
                              void* d_out, int out_size, void* d_ws, size_t ws_size,
                              hipStream_t stream) {
    const float* x     = (const float*)d_in[0];
    const float* w_in  = (const float*)d_in[1];
    const float* w_out = (const float*)d_in[2];
    float* out = (float*)d_out;
    char* ws = (char*)d_ws;

    double* theta_s = (double*)(ws);                    // 128 KB (storage order)
    int*    bin_s   = (int*)   (ws + 0x20000);          //  64 KB (storage order)
    double* energy  = (double*)(ws + 0x30000);          //  16*180*8 B
    float*  gain_s  = (float*) (ws + 0x40000);          //   1 MB
    float*  xe      = (float*) (ws + 0x140000);         //  16 MB
    // Dead-interval reuse of d_out (256 MiB, K5 rewrites all of it last):
    //   xpp (34 MB partial x_proj) at +128 MiB, dead after K2 reads it.
    //   fs  (32 MB spectra)        at +224 MiB, dead after K4 reads it.
    float*  xpp = (float*)((char*)d_out + ((size_t)128 << 20));
    float2* fs  = (float2*)((char*)d_out + ((size_t)224 << 20));

    (void)hipFuncSetAttribute((const void*)k_fft_fwd,
            hipFuncAttributeMaxDynamicSharedMemorySize, 131072);
    (void)hipFuncSetAttribute((const void*)k_fft_inv,
            hipFuncAttributeMaxDynamicSharedMemorySize, 131072);

    k0_tables<<<dim3(64), dim3(256), 0, stream>>>(theta_s, bin_s, energy);
    k1_proj  <<<dim3(16, 16, 2), dim3(256), 0, stream>>>(x, w_in, xpp);
    k_fft_fwd<<<dim3(256), dim3(1024), 131072, stream>>>(xpp, fs, bin_s, energy);
    k3_peaks <<<dim3(16), dim3(256), 0, stream>>>(energy, theta_s, bin_s, gain_s);
    k_fft_inv<<<dim3(256), dim3(1024), 131072, stream>>>(fs, gain_s, xe);
    k5_out   <<<dim3(16, 16, 16), dim3(256), 0, stream>>>(x, w_out, xe, out);
}